// Round 2
// baseline (615.918 us; speedup 1.0000x reference)
//
#include <hip/hip_runtime.h>
#include <hip/hip_bf16.h>

// Problem constants
constexpr int BB = 2;
constexpr int SS = 2048;
constexpr int EE = 1024;
constexpr int HH = 16;
constexpr int DD = 64;
constexpr int MM = BB * SS;  // 4096 rows in the projection GEMMs

typedef __attribute__((ext_vector_type(8))) short short8;    // 8 bf16 = 4 VGPRs (MFMA A/B frag)
typedef __attribute__((ext_vector_type(4))) float floatx4;   // MFMA C/D frag

__device__ inline short bf16bits(float x) {
    __hip_bfloat16 h = __float2bfloat16(x);
    return *reinterpret_cast<short*>(&h);
}

// Load 8 contiguous f32 and convert to a bf16x8 MFMA fragment.
__device__ inline short8 cvt8(const float* __restrict__ p) {
    const float4 a = reinterpret_cast<const float4*>(p)[0];
    const float4 b = reinterpret_cast<const float4*>(p)[1];
    short8 r;
    r[0] = bf16bits(a.x); r[1] = bf16bits(a.y); r[2] = bf16bits(a.z); r[3] = bf16bits(a.w);
    r[4] = bf16bits(b.x); r[5] = bf16bits(b.y); r[6] = bf16bits(b.z); r[7] = bf16bits(b.w);
    return r;
}

__device__ inline short8 ldg8bf(const __hip_bfloat16* p) {
    return *reinterpret_cast<const short8*>(p);
}

// ---------------------------------------------------------------------------
// Projection: Y = X @ W^T + b for q/k/v (blockIdx.z selects which).
// X: [M, E] f32 row-major.  W: [E, E] f32 row-major (nn.Linear layout).
// Inputs cast f32->bf16 in-register for MFMA. Q,K written bf16 as [B,H,S,D];
// V written transposed as [B,H,D,S] so the attention PV B-frag is contiguous.
// Tile: 128(M) x 64(N) per block, 4 waves; each wave owns 32 M-rows.
// ---------------------------------------------------------------------------
__global__ __launch_bounds__(256) void proj_kernel(
    const float* __restrict__ Xq,
    const float* __restrict__ Xk,
    const float* __restrict__ Xv,
    const float* __restrict__ Wq, const float* __restrict__ bq,
    const float* __restrict__ Wk, const float* __restrict__ bk,
    const float* __restrict__ Wv, const float* __restrict__ bv,
    __hip_bfloat16* __restrict__ qws,
    __hip_bfloat16* __restrict__ kws,
    __hip_bfloat16* __restrict__ vtws)
{
    const int which = blockIdx.z;
    const float* X    = (which == 0) ? Xq : (which == 1) ? Xk : Xv;
    const float* W    = (which == 0) ? Wq : (which == 1) ? Wk : Wv;
    const float* bias = (which == 0) ? bq : (which == 1) ? bk : bv;

    const int m0   = blockIdx.x * 128;
    const int n0   = blockIdx.y * 64;
    const int wave = threadIdx.x >> 6;
    const int lane = threadIdx.x & 63;
    const int l15  = lane & 15;
    const int quad = lane >> 4;

    floatx4 acc[2][4] = {};  // [m-subtile][n-subtile], each 16x16

    // A-frag rows this lane loads: A[m = lane&15][k = quad*8 + j]
    const float* arow0 = X + (size_t)(m0 + wave * 32 + l15) * EE + quad * 8;
    const float* arow1 = arow0 + (size_t)16 * EE;

    for (int k0 = 0; k0 < EE; k0 += 32) {
        short8 a0 = cvt8(arow0 + k0);
        short8 a1 = cvt8(arow1 + k0);
        #pragma unroll
        for (int nt = 0; nt < 4; ++nt) {
            // B-frag: B[k][n] = W[n][k]; lane: n = lane&15, k = quad*8+j (contig)
            short8 bfrag = cvt8(W + (size_t)(n0 + nt * 16 + l15) * EE + k0 + quad * 8);
            acc[0][nt] = __builtin_amdgcn_mfma_f32_16x16x32_bf16(a0, bfrag, acc[0][nt], 0, 0, 0);
            acc[1][nt] = __builtin_amdgcn_mfma_f32_16x16x32_bf16(a1, bfrag, acc[1][nt], 0, 0, 0);
        }
    }

    // Epilogue: C/D layout col = lane&15, row = quad*4 + r
    #pragma unroll
    for (int nt = 0; nt < 4; ++nt) {
        const int n = n0 + nt * 16 + l15;
        const float bval = bias[n];
        const int h = n >> 6, d = n & 63;
        #pragma unroll
        for (int mt = 0; mt < 2; ++mt) {
            #pragma unroll
            for (int r = 0; r < 4; ++r) {
                const int m = m0 + wave * 32 + mt * 16 + quad * 4 + r;
                const int b = m >> 11;          // m / SS
                const int s = m & (SS - 1);     // m % SS
                const __hip_bfloat16 hv = __float2bfloat16(acc[mt][nt][r] + bval);
                if (which == 0)
                    qws[(((size_t)b * HH + h) * SS + s) * DD + d] = hv;
                else if (which == 1)
                    kws[(((size_t)b * HH + h) * SS + s) * DD + d] = hv;
                else
                    vtws[(((size_t)b * HH + h) * DD + d) * SS + s] = hv;
            }
        }
    }
}

// ---------------------------------------------------------------------------
// Flash attention: one block = 64 q-rows of one (b,h); 4 waves x 16 q-rows.
// Online softmax over 32-key tiles. scale = 1/sqrt(EMBED_DIM) = 1/32.
// Masked keys (attn_mask[b,key]==0) contribute p = 0 explicitly.
// Output: f32 [B,H,S,D].
// ---------------------------------------------------------------------------
__global__ __launch_bounds__(256) void attn_kernel(
    const __hip_bfloat16* __restrict__ qws,
    const __hip_bfloat16* __restrict__ kws,
    const __hip_bfloat16* __restrict__ vtws,
    const int* __restrict__ amask,
    float* __restrict__ out)
{
    const int bh   = blockIdx.y;        // b*H + h
    const int b    = bh >> 4;           // / HH
    const int q0   = blockIdx.x * 64;
    const int wave = threadIdx.x >> 6;
    const int lane = threadIdx.x & 63;
    const int l15  = lane & 15;
    const int quad = lane >> 4;

    const __hip_bfloat16* Q  = qws  + (size_t)bh * SS * DD;
    const __hip_bfloat16* K  = kws  + (size_t)bh * SS * DD;
    const __hip_bfloat16* VT = vtws + (size_t)bh * DD * SS;
    const int* msk = amask + b * SS;

    // Q A-fragments for this wave's 16 rows, cached for the whole kernel
    const int qrow = q0 + wave * 16 + l15;
    const short8 qa0 = ldg8bf(Q + (size_t)qrow * DD + quad * 8);
    const short8 qa1 = ldg8bf(Q + (size_t)qrow * DD + 32 + quad * 8);

    float m_run[4], l_run[4];
    floatx4 acc[4] = {};  // 16(q) x 64(d) as 4 n-subtiles
    #pragma unroll
    for (int r = 0; r < 4; ++r) { m_run[r] = -1e30f; l_run[r] = 0.f; }

    __shared__ __align__(16) __hip_bfloat16 pshare[4][16 * 32];  // per-wave P buffer
    __hip_bfloat16* pw = pshare[wave];

    const float scale = 0.03125f;  // 1/sqrt(1024)

    for (int kt = 0; kt < SS; kt += 32) {
        // --- scores: 16(q) x 32(key) as two 16-col C-frags ---
        floatx4 s0 = {}, s1 = {};
        {
            const __hip_bfloat16* kp0 = K + (size_t)(kt + l15) * DD + quad * 8;
            s0 = __builtin_amdgcn_mfma_f32_16x16x32_bf16(qa0, ldg8bf(kp0),      s0, 0, 0, 0);
            s0 = __builtin_amdgcn_mfma_f32_16x16x32_bf16(qa1, ldg8bf(kp0 + 32), s0, 0, 0, 0);
            const __hip_bfloat16* kp1 = kp0 + 16 * DD;
            s1 = __builtin_amdgcn_mfma_f32_16x16x32_bf16(qa0, ldg8bf(kp1),      s1, 0, 0, 0);
            s1 = __builtin_amdgcn_mfma_f32_16x16x32_bf16(qa1, ldg8bf(kp1 + 32), s1, 0, 0, 0);
        }
        const bool keep0 = msk[kt + l15] != 0;
        const bool keep1 = msk[kt + 16 + l15] != 0;

        // --- online softmax (C-frag: col = lane&15 = key, row = quad*4+r = q) ---
        float alpha[4];
        #pragma unroll
        for (int r = 0; r < 4; ++r) {
            const float v0 = keep0 ? s0[r] * scale : -1e30f;
            const float v1 = keep1 ? s1[r] * scale : -1e30f;
            float mx = fmaxf(v0, v1);
            #pragma unroll
            for (int off = 1; off < 16; off <<= 1)
                mx = fmaxf(mx, __shfl_xor(mx, off, 64));
            const float mnew = fmaxf(m_run[r], mx);
            alpha[r] = __expf(m_run[r] - mnew);
            m_run[r] = mnew;
            const float p0 = keep0 ? __expf(v0 - mnew) : 0.f;  // masked -> exactly 0
            const float p1 = keep1 ? __expf(v1 - mnew) : 0.f;
            s0[r] = p0; s1[r] = p1;
            float ps = p0 + p1;
            #pragma unroll
            for (int off = 1; off < 16; off <<= 1)
                ps += __shfl_xor(ps, off, 64);
            l_run[r] = l_run[r] * alpha[r] + ps;
        }
        #pragma unroll
        for (int nt = 0; nt < 4; ++nt)
            #pragma unroll
            for (int r = 0; r < 4; ++r)
                acc[nt][r] *= alpha[r];

        // --- P: C-layout -> A-layout via per-wave LDS round-trip ---
        #pragma unroll
        for (int r = 0; r < 4; ++r) {
            pw[(quad * 4 + r) * 32 + l15]      = __float2bfloat16(s0[r]);
            pw[(quad * 4 + r) * 32 + 16 + l15] = __float2bfloat16(s1[r]);
        }
        __syncthreads();
        const short8 pa = *reinterpret_cast<const short8*>(&pw[l15 * 32 + quad * 8]);
        #pragma unroll
        for (int nt = 0; nt < 4; ++nt) {
            // B-frag: V[key][d]; lane: d = nt*16 + lane&15, key = kt + quad*8 + j
            // VT is [D,S] so this is an 8-element contiguous bf16 load.
            short8 vb = ldg8bf(VT + (size_t)(nt * 16 + l15) * SS + kt + quad * 8);
            acc[nt] = __builtin_amdgcn_mfma_f32_16x16x32_bf16(pa, vb, acc[nt], 0, 0, 0);
        }
        __syncthreads();  // WAR guard before next iteration overwrites pshare
    }

    // --- epilogue: out[b,h,q,d] = acc/l, f32 ---
    const size_t obase = (size_t)bh * SS * DD;
    #pragma unroll
    for (int nt = 0; nt < 4; ++nt) {
        #pragma unroll
        for (int r = 0; r < 4; ++r) {
            const int qq = q0 + wave * 16 + quad * 4 + r;
            const int d  = nt * 16 + l15;
            out[obase + (size_t)qq * DD + d] = acc[nt][r] / l_run[r];
        }
    }
}

extern "C" void kernel_launch(void* const* d_in, const int* in_sizes, int n_in,
                              void* d_out, int out_size, void* d_ws, size_t ws_size,
                              hipStream_t stream) {
    const float* q    = (const float*)d_in[0];
    const float* k    = (const float*)d_in[1];
    const float* v    = (const float*)d_in[2];
    const int*   mask = (const int*)d_in[3];
    const float* Wq   = (const float*)d_in[4];
    const float* bq   = (const float*)d_in[5];
    const float* Wk   = (const float*)d_in[6];
    const float* bk   = (const float*)d_in[7];
    const float* Wv   = (const float*)d_in[8];
    const float* bv   = (const float*)d_in[9];
    float* out = (float*)d_out;

    // Workspace: Q [B,H,S,D] | K [B,H,S,D] | V^T [B,H,D,S], bf16 (8 MiB each)
    __hip_bfloat16* qws  = (__hip_bfloat16*)d_ws;
    __hip_bfloat16* kws  = qws + (size_t)BB * HH * SS * DD;
    __hip_bfloat16* vtws = kws + (size_t)BB * HH * SS * DD;

    dim3 pgrid(MM / 128, EE / 64, 3);
    proj_kernel<<<pgrid, 256, 0, stream>>>(q, k, v, Wq, bq, Wk, bk, Wv, bv,
                                           qws, kws, vtws);

    dim3 agrid(SS / 64, BB * HH);
    attn_kernel<<<agrid, 256, 0, stream>>>(qws, kws, vtws, mask, out);
}

// Round 3
// 314.472 us; speedup vs baseline: 1.9586x; 1.9586x over previous
//
#include <hip/hip_runtime.h>
#include <hip/hip_bf16.h>

// Problem constants
constexpr int BB = 2;
constexpr int SS = 2048;
constexpr int EE = 1024;
constexpr int HH = 16;
constexpr int DD = 64;
constexpr int MM = BB * SS;  // 4096 rows in the projection GEMMs

typedef __attribute__((ext_vector_type(8))) short short8;    // 8 bf16 = 4 VGPRs (MFMA A/B frag)
typedef __attribute__((ext_vector_type(4))) float floatx4;   // MFMA C/D frag

__device__ inline short bf16bits(float x) {
    __hip_bfloat16 h = __float2bfloat16(x);
    return *reinterpret_cast<short*>(&h);
}

__device__ inline short8 pack8(const float4& a, const float4& b) {
    short8 r;
    r[0] = bf16bits(a.x); r[1] = bf16bits(a.y); r[2] = bf16bits(a.z); r[3] = bf16bits(a.w);
    r[4] = bf16bits(b.x); r[5] = bf16bits(b.y); r[6] = bf16bits(b.z); r[7] = bf16bits(b.w);
    return r;
}

// ---------------------------------------------------------------------------
// Projection: Y = X @ W^T + b for q/k/v (blockIdx.z selects which).
// 128x128 tile, K-step 32, LDS-staged with f32->bf16 convert-on-store and
// register prefetch of the next K-slice. 4 waves, each owns a 64x64 acc
// (4x4 16x16 subtiles, 16 MFMA / K-step / wave, 8 ds_read_b128 per 16 MFMA).
// LDS rows padded to 40 shorts (80 B): 16B-aligned for b128, 2-way bank
// aliasing only (free on CDNA4).
// Q,K written bf16 [B,H,S,D]; V written transposed [B,H,D,S].
// ---------------------------------------------------------------------------
__global__ __launch_bounds__(256) void proj_kernel(
    const float* __restrict__ Xq,
    const float* __restrict__ Xk,
    const float* __restrict__ Xv,
    const float* __restrict__ Wq, const float* __restrict__ bq,
    const float* __restrict__ Wk, const float* __restrict__ bk,
    const float* __restrict__ Wv, const float* __restrict__ bv,
    __hip_bfloat16* __restrict__ qws,
    __hip_bfloat16* __restrict__ kws,
    __hip_bfloat16* __restrict__ vtws)
{
    const int which = blockIdx.z;
    const float* X    = (which == 0) ? Xq : (which == 1) ? Xk : Xv;
    const float* W    = (which == 0) ? Wq : (which == 1) ? Wk : Wv;
    const float* bias = (which == 0) ? bq : (which == 1) ? bk : bv;

    const int m0   = blockIdx.x * 128;
    const int n0   = blockIdx.y * 128;
    const int tid  = threadIdx.x;
    const int wave = tid >> 6;
    const int lane = tid & 63;
    const int l15  = lane & 15;
    const int quad = lane >> 4;
    const int wr   = wave >> 1;   // wave's 64-row group
    const int wc   = wave & 1;    // wave's 64-col group

    __shared__ __align__(16) short As[128 * 40];
    __shared__ __align__(16) short Bs[128 * 40];

    // Staging map: thread -> (row = tid/2, half = tid%2) covering 16 f32.
    const int srow  = tid >> 1;
    const int shalf = tid & 1;
    const float* aSrc = X + (size_t)(m0 + srow) * EE + shalf * 16;
    const float* bSrc = W + (size_t)(n0 + srow) * EE + shalf * 16;
    short* aDst = As + srow * 40 + shalf * 16;
    short* bDst = Bs + srow * 40 + shalf * 16;

    floatx4 acc[4][4] = {};

    float4 pa[4], pb[4];
    #pragma unroll
    for (int i = 0; i < 4; ++i) {
        pa[i] = reinterpret_cast<const float4*>(aSrc)[i];
        pb[i] = reinterpret_cast<const float4*>(bSrc)[i];
    }

    for (int k0 = 0; k0 < EE; k0 += 32) {
        const short8 av0 = pack8(pa[0], pa[1]);
        const short8 av1 = pack8(pa[2], pa[3]);
        const short8 bv0 = pack8(pb[0], pb[1]);
        const short8 bv1 = pack8(pb[2], pb[3]);

        __syncthreads();  // WAR: previous iteration's frag reads done
        reinterpret_cast<short8*>(aDst)[0] = av0;
        reinterpret_cast<short8*>(aDst)[1] = av1;
        reinterpret_cast<short8*>(bDst)[0] = bv0;
        reinterpret_cast<short8*>(bDst)[1] = bv1;
        __syncthreads();  // staging visible

        // Prefetch next K-slice (overlaps with the MFMA block below)
        if (k0 + 32 < EE) {
            #pragma unroll
            for (int i = 0; i < 4; ++i) {
                pa[i] = reinterpret_cast<const float4*>(aSrc + k0 + 32)[i];
                pb[i] = reinterpret_cast<const float4*>(bSrc + k0 + 32)[i];
            }
        }

        short8 af[4], bf[4];
        #pragma unroll
        for (int mt = 0; mt < 4; ++mt)
            af[mt] = *reinterpret_cast<const short8*>(As + (wr * 64 + mt * 16 + l15) * 40 + quad * 8);
        #pragma unroll
        for (int nt = 0; nt < 4; ++nt)
            bf[nt] = *reinterpret_cast<const short8*>(Bs + (wc * 64 + nt * 16 + l15) * 40 + quad * 8);

        #pragma unroll
        for (int mt = 0; mt < 4; ++mt)
            #pragma unroll
            for (int nt = 0; nt < 4; ++nt)
                acc[mt][nt] = __builtin_amdgcn_mfma_f32_16x16x32_bf16(af[mt], bf[nt], acc[mt][nt], 0, 0, 0);
    }

    // Epilogue: C/D layout col = lane&15, row = quad*4 + r
    #pragma unroll
    for (int nt = 0; nt < 4; ++nt) {
        const int n = n0 + wc * 64 + nt * 16 + l15;
        const float bval = bias[n];
        const int h = n >> 6, d = n & 63;
        #pragma unroll
        for (int mt = 0; mt < 4; ++mt) {
            #pragma unroll
            for (int r = 0; r < 4; ++r) {
                const int m = m0 + wr * 64 + mt * 16 + quad * 4 + r;
                const int b = m >> 11;          // m / SS
                const int s = m & (SS - 1);     // m % SS
                const __hip_bfloat16 hv = __float2bfloat16(acc[mt][nt][r] + bval);
                if (which == 0)
                    qws[(((size_t)b * HH + h) * SS + s) * DD + d] = hv;
                else if (which == 1)
                    kws[(((size_t)b * HH + h) * SS + s) * DD + d] = hv;
                else
                    vtws[(((size_t)b * HH + h) * DD + d) * SS + s] = hv;
            }
        }
    }
}

// ---------------------------------------------------------------------------
// Flash attention: one block = 64 q-rows of one (b,h); 4 waves x 16 q-rows.
// 64-key tiles staged in LDS (shared by all 4 waves); online softmax;
// P LDS round-trip (verified C-layout -> A-layout transform); PV from LDS.
// LDS rows padded to 72 shorts (144 B): 16B-aligned, 2-way bank aliasing.
// ---------------------------------------------------------------------------
__global__ __launch_bounds__(256) void attn_kernel(
    const __hip_bfloat16* __restrict__ qws,
    const __hip_bfloat16* __restrict__ kws,
    const __hip_bfloat16* __restrict__ vtws,
    const int* __restrict__ amask,
    float* __restrict__ out)
{
    const int bh   = blockIdx.y;        // b*H + h
    const int b    = bh >> 4;           // / HH
    const int q0   = blockIdx.x * 64;
    const int tid  = threadIdx.x;
    const int wave = tid >> 6;
    const int lane = tid & 63;
    const int l15  = lane & 15;
    const int quad = lane >> 4;

    const __hip_bfloat16* Q  = qws  + (size_t)bh * SS * DD;
    const __hip_bfloat16* K  = kws  + (size_t)bh * SS * DD;
    const __hip_bfloat16* VT = vtws + (size_t)bh * DD * SS;
    const int* msk = amask + b * SS;

    __shared__ __align__(16) short Ks[64 * 72];      // [key][d]
    __shared__ __align__(16) short Vs[64 * 72];      // [d][key]
    __shared__ __align__(16) short Ps[4][16 * 72];   // per-wave P
    short* pw = Ps[wave];

    // Q A-fragments for this wave's 16 rows, cached for the whole kernel
    const int qrow = q0 + wave * 16 + l15;
    const short8 qa0 = *reinterpret_cast<const short8*>(Q + (size_t)qrow * DD + quad * 8);
    const short8 qa1 = *reinterpret_cast<const short8*>(Q + (size_t)qrow * DD + 32 + quad * 8);

    float m_run[4], l_run[4];
    floatx4 acc[4] = {};  // 16(q) x 64(d) as 4 d-subtiles
    #pragma unroll
    for (int r = 0; r < 4; ++r) { m_run[r] = -1e30f; l_run[r] = 0.f; }

    const float scale = 0.03125f;  // 1/sqrt(1024)

    for (int kt = 0; kt < SS; kt += 64) {
        __syncthreads();  // WAR: previous tile's Ks/Vs/P reads done

        // --- stage K (64 keys x 64 d) and V^T (64 d x 64 keys) ---
        #pragma unroll
        for (int p = 0; p < 2; ++p) {
            const int flat = tid + p * 256;
            const int row = flat >> 3;      // 0..63
            const int g   = flat & 7;       // 8-bf16 group
            *reinterpret_cast<short8*>(Ks + row * 72 + g * 8) =
                *reinterpret_cast<const short8*>(K + (size_t)(kt + row) * DD + g * 8);
            *reinterpret_cast<short8*>(Vs + row * 72 + g * 8) =
                *reinterpret_cast<const short8*>(VT + (size_t)row * SS + kt + g * 8);
        }
        __syncthreads();  // staging visible

        // --- scores: 16(q) x 64(key) as 4 C-frags ---
        floatx4 s[4] = {};
        #pragma unroll
        for (int nt = 0; nt < 4; ++nt) {
            const short8 kb0 = *reinterpret_cast<const short8*>(Ks + (nt * 16 + l15) * 72 + quad * 8);
            const short8 kb1 = *reinterpret_cast<const short8*>(Ks + (nt * 16 + l15) * 72 + 32 + quad * 8);
            s[nt] = __builtin_amdgcn_mfma_f32_16x16x32_bf16(qa0, kb0, s[nt], 0, 0, 0);
            s[nt] = __builtin_amdgcn_mfma_f32_16x16x32_bf16(qa1, kb1, s[nt], 0, 0, 0);
        }
        bool keep[4];
        #pragma unroll
        for (int nt = 0; nt < 4; ++nt) keep[nt] = msk[kt + nt * 16 + l15] != 0;

        // --- online softmax (C-frag: col = lane&15 = key, row = quad*4+r = q) ---
        float alpha[4];
        #pragma unroll
        for (int r = 0; r < 4; ++r) {
            float v[4];
            #pragma unroll
            for (int nt = 0; nt < 4; ++nt)
                v[nt] = keep[nt] ? s[nt][r] * scale : -1e30f;
            float mx = fmaxf(fmaxf(v[0], v[1]), fmaxf(v[2], v[3]));
            #pragma unroll
            for (int off = 1; off < 16; off <<= 1)
                mx = fmaxf(mx, __shfl_xor(mx, off, 64));
            const float mnew = fmaxf(m_run[r], mx);
            alpha[r] = __expf(m_run[r] - mnew);
            m_run[r] = mnew;
            float ps = 0.f;
            #pragma unroll
            for (int nt = 0; nt < 4; ++nt) {
                const float p = keep[nt] ? __expf(v[nt] - mnew) : 0.f;
                s[nt][r] = p;
                ps += p;
            }
            #pragma unroll
            for (int off = 1; off < 16; off <<= 1)
                ps += __shfl_xor(ps, off, 64);
            l_run[r] = l_run[r] * alpha[r] + ps;
        }
        #pragma unroll
        for (int nt = 0; nt < 4; ++nt)
            #pragma unroll
            for (int r = 0; r < 4; ++r)
                acc[nt][r] *= alpha[r];

        // --- P: C-layout -> A-layout via per-wave LDS round-trip ---
        #pragma unroll
        for (int r = 0; r < 4; ++r)
            #pragma unroll
            for (int nt = 0; nt < 4; ++nt)
                pw[(quad * 4 + r) * 72 + nt * 16 + l15] = bf16bits(s[nt][r]);
        __syncthreads();  // P visible (and Vs reads ordered vs next staging)

        // --- PV ---
        const short8 pa0 = *reinterpret_cast<const short8*>(pw + l15 * 72 + quad * 8);
        const short8 pa1 = *reinterpret_cast<const short8*>(pw + l15 * 72 + 32 + quad * 8);
        #pragma unroll
        for (int nt = 0; nt < 4; ++nt) {
            const short8 vb0 = *reinterpret_cast<const short8*>(Vs + (nt * 16 + l15) * 72 + quad * 8);
            const short8 vb1 = *reinterpret_cast<const short8*>(Vs + (nt * 16 + l15) * 72 + 32 + quad * 8);
            acc[nt] = __builtin_amdgcn_mfma_f32_16x16x32_bf16(pa0, vb0, acc[nt], 0, 0, 0);
            acc[nt] = __builtin_amdgcn_mfma_f32_16x16x32_bf16(pa1, vb1, acc[nt], 0, 0, 0);
        }
    }

    // --- epilogue: out[b,h,q,d] = acc/l, f32 ---
    const size_t obase = (size_t)bh * SS * DD;
    #pragma unroll
    for (int nt = 0; nt < 4; ++nt) {
        #pragma unroll
        for (int r = 0; r < 4; ++r) {
            const int qq = q0 + wave * 16 + quad * 4 + r;
            const int d  = nt * 16 + l15;
            out[obase + (size_t)qq * DD + d] = acc[nt][r] / l_run[r];
        }
    }
}

extern "C" void kernel_launch(void* const* d_in, const int* in_sizes, int n_in,
                              void* d_out, int out_size, void* d_ws, size_t ws_size,
                              hipStream_t stream) {
    const float* q    = (const float*)d_in[0];
    const float* k    = (const float*)d_in[1];
    const float* v    = (const float*)d_in[2];
    const int*   mask = (const int*)d_in[3];
    const float* Wq   = (const float*)d_in[4];
    const float* bq   = (const float*)d_in[5];
    const float* Wk   = (const float*)d_in[6];
    const float* bk   = (const float*)d_in[7];
    const float* Wv   = (const float*)d_in[8];
    const float* bv   = (const float*)d_in[9];
    float* out = (float*)d_out;

    // Workspace: Q [B,H,S,D] | K [B,H,S,D] | V^T [B,H,D,S], bf16 (8 MiB each)
    __hip_bfloat16* qws  = (__hip_bfloat16*)d_ws;
    __hip_bfloat16* kws  = qws + (size_t)BB * HH * SS * DD;
    __hip_bfloat16* vtws = kws + (size_t)BB * HH * SS * DD;

    dim3 pgrid(MM / 128, EE / 128, 3);
    proj_kernel<<<pgrid, 256, 0, stream>>>(q, k, v, Wq, bq, Wk, bk, Wv, bv,
                                           qws, kws, vtws);

    dim3 agrid(SS / 64, BB * HH);
    attn_kernel<<<agrid, 256, 0, stream>>>(qws, kws, vtws, mask, out);
}

// Round 4
// 235.302 us; speedup vs baseline: 2.6176x; 1.3365x over previous
//
#include <hip/hip_runtime.h>
#include <hip/hip_bf16.h>

// Problem constants
constexpr int BB = 2;
constexpr int SS = 2048;
constexpr int EE = 1024;
constexpr int HH = 16;
constexpr int DD = 64;
constexpr int MM = BB * SS;              // 4096 rows in the projection GEMMs
constexpr int CX = MM * EE;              // 4194304 elems per X slice
constexpr int CW = EE * EE;              // 1048576 elems per W slice
// Q pre-scale: 1/sqrt(EMBED_DIM) * log2(e) so attention scores are base-2 logits
#define QSCALE 0.045084220027780106f
#define NEGBIG -1e30f

typedef __attribute__((ext_vector_type(8))) short short8;    // 8 bf16 = 4 VGPRs (MFMA A/B frag)
typedef __attribute__((ext_vector_type(4))) float floatx4;   // MFMA C/D frag

__device__ inline short bf16bits(float x) {
    __hip_bfloat16 h = __float2bfloat16(x);
    return *reinterpret_cast<short*>(&h);
}

__device__ inline unsigned pkbf(float a, float b) {
    return (unsigned)(unsigned short)bf16bits(a) |
           ((unsigned)(unsigned short)bf16bits(b) << 16);
}

__device__ inline float fast_exp2(float x) {
#if __has_builtin(__builtin_amdgcn_exp2f)
    return __builtin_amdgcn_exp2f(x);
#else
    return exp2f(x);
#endif
}

// Async global->LDS, 16 B per lane. LDS dest is wave-uniform base + lane*16.
__device__ inline void gl_lds16(const __hip_bfloat16* g, short* l) {
    __builtin_amdgcn_global_load_lds(
        (const __attribute__((address_space(1))) void*)g,
        (__attribute__((address_space(3))) void*)l, 16, 0, 0);
}

// ---------------------------------------------------------------------------
// Convert pass: f32 -> bf16 for the 3 X inputs and 3 W matrices.
// z = 0..2: X slices (CX elems), z = 3..5: W slices (CW elems).
// ---------------------------------------------------------------------------
__global__ __launch_bounds__(256) void convert_kernel(
    const float* __restrict__ x0, const float* __restrict__ x1, const float* __restrict__ x2,
    const float* __restrict__ w0, const float* __restrict__ w1, const float* __restrict__ w2,
    __hip_bfloat16* __restrict__ xb, __hip_bfloat16* __restrict__ wb)
{
    const int z = blockIdx.z;
    const float* src;
    __hip_bfloat16* dst;
    int count;
    if (z < 3) {
        src = (z == 0) ? x0 : (z == 1) ? x1 : x2;
        dst = xb + (size_t)z * CX;
        count = CX;
    } else {
        src = (z == 3) ? w0 : (z == 4) ? w1 : w2;
        dst = wb + (size_t)(z - 3) * CW;
        count = CW;
    }
    const int idx = (blockIdx.x * 256 + threadIdx.x) * 8;
    if (idx >= count) return;
    const float4 a = reinterpret_cast<const float4*>(src + idx)[0];
    const float4 b = reinterpret_cast<const float4*>(src + idx)[1];
    short8 r;
    r[0] = bf16bits(a.x); r[1] = bf16bits(a.y); r[2] = bf16bits(a.z); r[3] = bf16bits(a.w);
    r[4] = bf16bits(b.x); r[5] = bf16bits(b.y); r[6] = bf16bits(b.z); r[7] = bf16bits(b.w);
    *reinterpret_cast<short8*>(dst + idx) = r;
}

__global__ __launch_bounds__(256) void maskbias_kernel(
    const int* __restrict__ am, float* __restrict__ mb)
{
    const int i = blockIdx.x * 256 + threadIdx.x;
    if (i < BB * SS) mb[i] = (am[i] != 0) ? 0.f : NEGBIG;
}

// ---------------------------------------------------------------------------
// Projection GEMM (m97 structure): Y = Xbf @ Wbf^T + b, all bf16 in LDS.
// 128x128 tile, BK=32, global_load_lds width-16 staging, 4 waves each owning
// a 64x64 accumulator (16 MFMA per K-step per wave).
// which==0 output (Q) is pre-scaled by QSCALE. V stored transposed [B,H,D,S].
// ---------------------------------------------------------------------------
__global__ __launch_bounds__(256) void proj_gemm(
    const __hip_bfloat16* __restrict__ xb,
    const __hip_bfloat16* __restrict__ wb,
    const float* __restrict__ bq, const float* __restrict__ bk, const float* __restrict__ bv,
    __hip_bfloat16* __restrict__ qws,
    __hip_bfloat16* __restrict__ kws,
    __hip_bfloat16* __restrict__ vtws)
{
    const int which = blockIdx.z;
    const __hip_bfloat16* A = xb + (size_t)which * CX;
    const __hip_bfloat16* W = wb + (size_t)which * CW;
    const float* bias = (which == 0) ? bq : (which == 1) ? bk : bv;

    const int m0   = blockIdx.x * 128;
    const int n0   = blockIdx.y * 128;
    const int tid  = threadIdx.x;
    const int wave = tid >> 6;
    const int lane = tid & 63;
    const int l15  = lane & 15;
    const int quad = lane >> 4;
    const int wr   = wave >> 1;
    const int wc   = wave & 1;

    __shared__ __align__(16) short As[128 * 32];
    __shared__ __align__(16) short Bs[128 * 32];

    // global_load_lds mapping: lane l covers row (w*16 + l/4), k-group (l&3)*8
    const int lrow = (lane >> 2);
    const int lk   = (lane & 3) * 8;

    floatx4 acc[4][4] = {};

    for (int k0 = 0; k0 < EE; k0 += 32) {
        __syncthreads();  // WAR: previous iteration's frag reads complete
        #pragma unroll
        for (int i = 0; i < 2; ++i) {
            gl_lds16(A + (size_t)(m0 + i * 64 + wave * 16 + lrow) * EE + k0 + lk,
                     As + (i * 64 + wave * 16) * 32);
            gl_lds16(W + (size_t)(n0 + i * 64 + wave * 16 + lrow) * EE + k0 + lk,
                     Bs + (i * 64 + wave * 16) * 32);
        }
        __syncthreads();  // staging visible (drains vmcnt)

        short8 af[4], bf[4];
        #pragma unroll
        for (int mt = 0; mt < 4; ++mt)
            af[mt] = *reinterpret_cast<const short8*>(As + (wr * 64 + mt * 16 + l15) * 32 + quad * 8);
        #pragma unroll
        for (int nt = 0; nt < 4; ++nt)
            bf[nt] = *reinterpret_cast<const short8*>(Bs + (wc * 64 + nt * 16 + l15) * 32 + quad * 8);

        #pragma unroll
        for (int mt = 0; mt < 4; ++mt)
            #pragma unroll
            for (int nt = 0; nt < 4; ++nt)
                acc[mt][nt] = __builtin_amdgcn_mfma_f32_16x16x32_bf16(af[mt], bf[nt], acc[mt][nt], 0, 0, 0);
    }

    // Epilogue: C/D layout col = lane&15, row = quad*4 + r
    #pragma unroll
    for (int nt = 0; nt < 4; ++nt) {
        const int n = n0 + wc * 64 + nt * 16 + l15;
        const float bval = bias[n];
        const int h = n >> 6, d = n & 63;
        #pragma unroll
        for (int mt = 0; mt < 4; ++mt) {
            #pragma unroll
            for (int r = 0; r < 4; ++r) {
                const int m = m0 + wr * 64 + mt * 16 + quad * 4 + r;
                const int b = m >> 11;
                const int s = m & (SS - 1);
                float val = acc[mt][nt][r] + bval;
                if (which == 0) val *= QSCALE;   // fold softmax scale+log2e into Q
                const __hip_bfloat16 hv = __float2bfloat16(val);
                if (which == 0)
                    qws[(((size_t)b * HH + h) * SS + s) * DD + d] = hv;
                else if (which == 1)
                    kws[(((size_t)b * HH + h) * SS + s) * DD + d] = hv;
                else
                    vtws[(((size_t)b * HH + h) * DD + d) * SS + s] = hv;
            }
        }
    }
}

// ---------------------------------------------------------------------------
// Flash attention, transposed-score form. One block = 64 q-rows of one (b,h);
// 4 waves x 16 q. Scores computed as S^T = K·Q^T so each lane (q = lane&15)
// holds 16 in-lane key-scores -> softmax reductions are in-lane + 2 shuffles.
// Mask folded in as additive bias (0 / -1e30); Q pre-scaled (QSCALE) so
// exp2 is used directly. P round-trips through per-wave LDS (b32 packed
// stores). acc C-layout: col = d, row = q.
// ---------------------------------------------------------------------------
__global__ __launch_bounds__(256) void attn_kernel(
    const __hip_bfloat16* __restrict__ qws,
    const __hip_bfloat16* __restrict__ kws,
    const __hip_bfloat16* __restrict__ vtws,
    const float* __restrict__ maskbias,
    float* __restrict__ out)
{
    const int bh   = blockIdx.y;
    const int b    = bh >> 4;
    const int q0   = blockIdx.x * 64;
    const int tid  = threadIdx.x;
    const int wave = tid >> 6;
    const int lane = tid & 63;
    const int l15  = lane & 15;
    const int quad = lane >> 4;

    const __hip_bfloat16* Q  = qws  + (size_t)bh * SS * DD;
    const __hip_bfloat16* K  = kws  + (size_t)bh * SS * DD;
    const __hip_bfloat16* VT = vtws + (size_t)bh * DD * SS;
    const float* mb = maskbias + b * SS;

    __shared__ __align__(16) short Ks[64 * 72];      // [key][d], padded rows
    __shared__ __align__(16) short Vs[64 * 72];      // [d][key]
    __shared__ __align__(16) short Ps[4][16 * 72];   // per-wave P[q][key]
    short* pw = Ps[wave];

    // Q fragment (B-operand for S^T, A-operand layout-identical): q = l15
    const int qrow = q0 + wave * 16 + l15;
    const short8 qa0 = *reinterpret_cast<const short8*>(Q + (size_t)qrow * DD + quad * 8);
    const short8 qa1 = *reinterpret_cast<const short8*>(Q + (size_t)qrow * DD + 32 + quad * 8);

    float m_run = NEGBIG, l_run = 0.f;   // per-lane: q = l15 (replicated over quads)
    floatx4 acc[4] = {};                 // O: col = d (l15), row = q (quad*4+r)

    for (int kt = 0; kt < SS; kt += 64) {
        __syncthreads();  // WAR: previous tile's LDS reads done

        // stage K-tile [64key x 64d] and V^T-tile [64d x 64key]
        #pragma unroll
        for (int p = 0; p < 2; ++p) {
            const int flat = tid + p * 256;
            const int row = flat >> 3;
            const int g   = flat & 7;
            *reinterpret_cast<short8*>(Ks + row * 72 + g * 8) =
                *reinterpret_cast<const short8*>(K + (size_t)(kt + row) * DD + g * 8);
            *reinterpret_cast<short8*>(Vs + row * 72 + g * 8) =
                *reinterpret_cast<const short8*>(VT + (size_t)row * SS + kt + g * 8);
        }
        __syncthreads();  // staging visible

        // --- S^T: st[f] holds keys f*16+quad*4+r (rows), q = l15 (cols) ---
        floatx4 st[4];
        #pragma unroll
        for (int f = 0; f < 4; ++f) {
            const short8 ka = *reinterpret_cast<const short8*>(Ks + (f * 16 + l15) * 72 + quad * 8);
            const short8 kb = *reinterpret_cast<const short8*>(Ks + (f * 16 + l15) * 72 + 32 + quad * 8);
            floatx4 z = {};
            z = __builtin_amdgcn_mfma_f32_16x16x32_bf16(ka, qa0, z, 0, 0, 0);
            z = __builtin_amdgcn_mfma_f32_16x16x32_bf16(kb, qa1, z, 0, 0, 0);
            st[f] = z;
        }

        // --- add mask bias (keys are in-lane: float4 over r) ---
        #pragma unroll
        for (int f = 0; f < 4; ++f) {
            const float4 m4 = *reinterpret_cast<const float4*>(mb + kt + f * 16 + quad * 4);
            st[f][0] += m4.x; st[f][1] += m4.y; st[f][2] += m4.z; st[f][3] += m4.w;
        }

        // --- online softmax: in-lane over 16, cross-quad via 2 shuffles ---
        float mx = st[0][0];
        #pragma unroll
        for (int f = 0; f < 4; ++f)
            #pragma unroll
            for (int r = 0; r < 4; ++r)
                mx = fmaxf(mx, st[f][r]);
        mx = fmaxf(mx, __shfl_xor(mx, 16, 64));
        mx = fmaxf(mx, __shfl_xor(mx, 32, 64));

        const float mnew = fmaxf(m_run, mx);
        const float alpha = fast_exp2(m_run - mnew);
        m_run = mnew;

        float psum = 0.f;
        #pragma unroll
        for (int f = 0; f < 4; ++f)
            #pragma unroll
            for (int r = 0; r < 4; ++r) {
                const float p = fast_exp2(st[f][r] - mnew);
                st[f][r] = p;
                psum += p;
            }
        psum += __shfl_xor(psum, 16, 64);
        psum += __shfl_xor(psum, 32, 64);
        l_run = l_run * alpha + psum;

        // --- store P[q=l15][key] as packed bf16 pairs (b32 stores) ---
        #pragma unroll
        for (int f = 0; f < 4; ++f) {
            *reinterpret_cast<unsigned*>(pw + l15 * 72 + f * 16 + quad * 4) =
                pkbf(st[f][0], st[f][1]);
            *reinterpret_cast<unsigned*>(pw + l15 * 72 + f * 16 + quad * 4 + 2) =
                pkbf(st[f][2], st[f][3]);
        }
        __asm__ volatile("s_waitcnt lgkmcnt(0)" ::: "memory");  // wave-local P drain

        const short8 pa0 = *reinterpret_cast<const short8*>(pw + l15 * 72 + quad * 8);
        const short8 pa1 = *reinterpret_cast<const short8*>(pw + l15 * 72 + 32 + quad * 8);

        // --- rescale acc by alpha (per q row -> broadcast from lane q) ---
        float alphaq[4];
        #pragma unroll
        for (int r = 0; r < 4; ++r)
            alphaq[r] = __shfl(alpha, quad * 4 + r, 16);
        #pragma unroll
        for (int nt = 0; nt < 4; ++nt)
            #pragma unroll
            for (int r = 0; r < 4; ++r)
                acc[nt][r] *= alphaq[r];

        // --- PV: O[q][d] += P[q][key] V[key][d] ---
        #pragma unroll
        for (int nt = 0; nt < 4; ++nt) {
            const short8 vb0 = *reinterpret_cast<const short8*>(Vs + (nt * 16 + l15) * 72 + quad * 8);
            const short8 vb1 = *reinterpret_cast<const short8*>(Vs + (nt * 16 + l15) * 72 + 32 + quad * 8);
            acc[nt] = __builtin_amdgcn_mfma_f32_16x16x32_bf16(pa0, vb0, acc[nt], 0, 0, 0);
            acc[nt] = __builtin_amdgcn_mfma_f32_16x16x32_bf16(pa1, vb1, acc[nt], 0, 0, 0);
        }
    }

    // --- epilogue ---
    float lq[4];
    #pragma unroll
    for (int r = 0; r < 4; ++r)
        lq[r] = __shfl(l_run, quad * 4 + r, 16);
    const size_t obase = (size_t)bh * SS * DD;
    #pragma unroll
    for (int nt = 0; nt < 4; ++nt)
        #pragma unroll
        for (int r = 0; r < 4; ++r) {
            const int qq = q0 + wave * 16 + quad * 4 + r;
            const int d  = nt * 16 + l15;
            out[obase + (size_t)qq * DD + d] = acc[nt][r] / lq[r];
        }
}

extern "C" void kernel_launch(void* const* d_in, const int* in_sizes, int n_in,
                              void* d_out, int out_size, void* d_ws, size_t ws_size,
                              hipStream_t stream) {
    const float* q    = (const float*)d_in[0];
    const float* k    = (const float*)d_in[1];
    const float* v    = (const float*)d_in[2];
    const int*   mask = (const int*)d_in[3];
    const float* Wq   = (const float*)d_in[4];
    const float* bq   = (const float*)d_in[5];
    const float* Wk   = (const float*)d_in[6];
    const float* bk   = (const float*)d_in[7];
    const float* Wv   = (const float*)d_in[8];
    const float* bv   = (const float*)d_in[9];
    float* out = (float*)d_out;

    // Workspace layout (shorts): qws | kws | vtws | Xbf(3) | Wbf(3) | maskbias(f32)
    __hip_bfloat16* qws  = (__hip_bfloat16*)d_ws;
    __hip_bfloat16* kws  = qws + (size_t)CX;
    __hip_bfloat16* vtws = kws + (size_t)CX;
    __hip_bfloat16* xb   = vtws + (size_t)CX;
    __hip_bfloat16* wb   = xb + (size_t)3 * CX;
    float* mbias = (float*)(wb + (size_t)3 * CW);

    convert_kernel<<<dim3(CX / (256 * 8), 1, 6), 256, 0, stream>>>(
        q, k, v, Wq, Wk, Wv, xb, wb);
    maskbias_kernel<<<dim3((BB * SS) / 256), 256, 0, stream>>>(mask, mbias);
    proj_gemm<<<dim3(MM / 128, EE / 128, 3), 256, 0, stream>>>(
        xb, wb, bq, bk, bv, qws, kws, vtws);
    attn_kernel<<<dim3(SS / 64, BB * HH), 256, 0, stream>>>(
        qws, kws, vtws, mbias, out);
}